// Round 1
// baseline (120.351 us; speedup 1.0000x reference)
//
#include <hip/hip_runtime.h>

// Separable QP projection via bisection on lambda.
// One 256-thread block per row (B=4096, N=4096).
// Each thread owns 16 elements of the row, kept in registers across all
// 40 bisection iterations (z, 1/(2*gamma), m, M -> 64 VGPRs of state).
// Per iteration: 16x {fma, clip(med3), add} per thread, wave shfl_xor
// reduce, 4-slot LDS combine, uniform lo/hi update on every thread.

#define BISECT_ITERS 40

__global__ __launch_bounds__(256) void qp_proj_n4096(
    const float* __restrict__ z,
    const float* __restrict__ gamma,
    const float* __restrict__ mlo,
    const float* __restrict__ mhi,
    const float* __restrict__ xi,
    float* __restrict__ out)
{
    constexpr int N = 4096;
    const int row  = blockIdx.x;
    const int tid  = threadIdx.x;     // 0..255
    const int lane = tid & 63;
    const int wid  = tid >> 6;        // 0..3

    const float4* zrow = reinterpret_cast<const float4*>(z + (size_t)row * N);
    const float4* g4   = reinterpret_cast<const float4*>(gamma);
    const float4* m4   = reinterpret_cast<const float4*>(mlo);
    const float4* M4   = reinterpret_cast<const float4*>(mhi);
    float4*       orow = reinterpret_cast<float4*>(out + (size_t)row * N);

    // Per-thread element state (static indices after full unroll -> registers).
    float za[16], ia[16], ma[16], Ma[16];

    float pmin =  INFINITY;   // partial min of 2g*(m - z)
    float pmax = -INFINITY;   // partial max of 2g*(M - z)

    #pragma unroll
    for (int k = 0; k < 4; ++k) {
        const int idx = tid + k * 256;           // float4 index, coalesced
        const float4 zz = zrow[idx];
        const float4 gg = g4[idx];
        const float4 mm = m4[idx];
        const float4 MM = M4[idx];

        const float zs[4] = {zz.x, zz.y, zz.z, zz.w};
        const float gs[4] = {gg.x, gg.y, gg.z, gg.w};
        const float ms[4] = {mm.x, mm.y, mm.z, mm.w};
        const float Ms[4] = {MM.x, MM.y, MM.z, MM.w};

        #pragma unroll
        for (int c = 0; c < 4; ++c) {
            const int j = 4 * k + c;
            const float tg = 2.0f * gs[c];
            za[j] = zs[c];
            ia[j] = 1.0f / tg;
            ma[j] = ms[c];
            Ma[j] = Ms[c];
            pmin = fminf(pmin, tg * (ms[c] - zs[c]));
            pmax = fmaxf(pmax, tg * (Ms[c] - zs[c]));
        }
    }

    // ---- block reduce initial bounds ----
    __shared__ float wmin[4], wmax[4], wsum[4];

    #pragma unroll
    for (int o = 32; o > 0; o >>= 1) {
        pmin = fminf(pmin, __shfl_xor(pmin, o, 64));
        pmax = fmaxf(pmax, __shfl_xor(pmax, o, 64));
    }
    if (lane == 0) { wmin[wid] = pmin; wmax[wid] = pmax; }
    __syncthreads();
    float lo = fminf(fminf(wmin[0], wmin[1]), fminf(wmin[2], wmin[3]));
    float hi = fmaxf(fmaxf(wmax[0], wmax[1]), fmaxf(wmax[2], wmax[3]));

    const float xir = xi[row];

    // ---- bisection ----
    for (int it = 0; it < BISECT_ITERS; ++it) {
        const float mid = 0.5f * (lo + hi);
        float s = 0.0f;
        #pragma unroll
        for (int j = 0; j < 16; ++j) {
            float x = fmaf(mid, ia[j], za[j]);
            x = fminf(fmaxf(x, ma[j]), Ma[j]);   // med3
            s += x;
        }
        #pragma unroll
        for (int o = 32; o > 0; o >>= 1) s += __shfl_xor(s, o, 64);
        if (lane == 0) wsum[wid] = s;
        __syncthreads();
        const float gmid = (wsum[0] + wsum[1] + wsum[2] + wsum[3]) - xir;
        __syncthreads();   // reads done before next iter's leader writes
        if (gmid > 0.0f) hi = mid; else lo = mid;
    }

    const float lam = 0.5f * (lo + hi);

    // ---- final x ----
    #pragma unroll
    for (int k = 0; k < 4; ++k) {
        const int idx = tid + k * 256;
        float4 r;
        float xs[4];
        #pragma unroll
        for (int c = 0; c < 4; ++c) {
            const int j = 4 * k + c;
            float x = fmaf(lam, ia[j], za[j]);
            xs[c] = fminf(fmaxf(x, ma[j]), Ma[j]);
        }
        r.x = xs[0]; r.y = xs[1]; r.z = xs[2]; r.w = xs[3];
        orow[idx] = r;
    }
}

extern "C" void kernel_launch(void* const* d_in, const int* in_sizes, int n_in,
                              void* d_out, int out_size, void* d_ws, size_t ws_size,
                              hipStream_t stream) {
    const float* z     = (const float*)d_in[0];
    const float* gamma = (const float*)d_in[1];
    const float* m     = (const float*)d_in[2];
    const float* M     = (const float*)d_in[3];
    const float* xi    = (const float*)d_in[4];
    float* out = (float*)d_out;

    const int B = in_sizes[4];   // rows (xi has one entry per row)
    // Kernel is specialized to N == 4096 (16 elements / thread, 256 threads).
    qp_proj_n4096<<<dim3(B), dim3(256), 0, stream>>>(z, gamma, m, M, xi, out);
}

// Round 2
// 43.581 us; speedup vs baseline: 2.7615x; 2.7615x over previous
//
#include <hip/hip_runtime.h>

// Separable QP projection via bisection on lambda.
// One 256-thread block per row (B=4096, N=4096).
// Each thread owns 16 elements of the row in registers across all
// bisection iterations (z, 1/(2*gamma), m, M).
// Per iteration: 16x {fma, med3, add} per thread, wave shfl_xor reduce,
// double-buffered 4-slot LDS combine (ONE barrier/iter), uniform lo/hi update.
//
// ITERS=16 (not the reference's 40): initial interval width ~20, so
// |lam - lam*| <= 20/2^17 ~ 1.5e-4 -> x error <= 8e-5, vs 2e-2 threshold.

#define BISECT_ITERS 16

__global__ __launch_bounds__(256) void qp_proj_n4096(
    const float* __restrict__ z,
    const float* __restrict__ gamma,
    const float* __restrict__ mlo,
    const float* __restrict__ mhi,
    const float* __restrict__ xi,
    float* __restrict__ out)
{
    constexpr int N = 4096;
    const int row  = blockIdx.x;
    const int tid  = threadIdx.x;     // 0..255
    const int lane = tid & 63;
    const int wid  = tid >> 6;        // 0..3

    const float4* zrow = reinterpret_cast<const float4*>(z + (size_t)row * N);
    const float4* g4   = reinterpret_cast<const float4*>(gamma);
    const float4* m4   = reinterpret_cast<const float4*>(mlo);
    const float4* M4   = reinterpret_cast<const float4*>(mhi);
    float4*       orow = reinterpret_cast<float4*>(out + (size_t)row * N);

    // Per-thread element state (static indices after full unroll -> registers).
    float za[16], ia[16], ma[16], Ma[16];

    float pmin =  INFINITY;   // partial min of 2g*(m - z)
    float pmax = -INFINITY;   // partial max of 2g*(M - z)

    #pragma unroll
    for (int k = 0; k < 4; ++k) {
        const int idx = tid + k * 256;           // float4 index, coalesced
        const float4 zz = zrow[idx];
        const float4 gg = g4[idx];
        const float4 mm = m4[idx];
        const float4 MM = M4[idx];

        const float zs[4] = {zz.x, zz.y, zz.z, zz.w};
        const float gs[4] = {gg.x, gg.y, gg.z, gg.w};
        const float ms[4] = {mm.x, mm.y, mm.z, mm.w};
        const float Ms[4] = {MM.x, MM.y, MM.z, MM.w};

        #pragma unroll
        for (int c = 0; c < 4; ++c) {
            const int j = 4 * k + c;
            const float tg = 2.0f * gs[c];
            za[j] = zs[c];
            ia[j] = 1.0f / tg;
            ma[j] = ms[c];
            Ma[j] = Ms[c];
            pmin = fminf(pmin, tg * (ms[c] - zs[c]));
            pmax = fmaxf(pmax, tg * (Ms[c] - zs[c]));
        }
    }

    // ---- block reduce initial bounds ----
    __shared__ float wmin[4], wmax[4];
    __shared__ float wsum[2][4];      // double-buffered: one barrier per iter

    #pragma unroll
    for (int o = 32; o > 0; o >>= 1) {
        pmin = fminf(pmin, __shfl_xor(pmin, o, 64));
        pmax = fmaxf(pmax, __shfl_xor(pmax, o, 64));
    }
    if (lane == 0) { wmin[wid] = pmin; wmax[wid] = pmax; }
    __syncthreads();
    float lo = fminf(fminf(wmin[0], wmin[1]), fminf(wmin[2], wmin[3]));
    float hi = fmaxf(fmaxf(wmax[0], wmax[1]), fmaxf(wmax[2], wmax[3]));

    const float xir = xi[row];

    // ---- bisection ----
    for (int it = 0; it < BISECT_ITERS; ++it) {
        const float mid = 0.5f * (lo + hi);
        float t[16];
        #pragma unroll
        for (int j = 0; j < 16; ++j) {
            const float x = fmaf(mid, ia[j], za[j]);
            t[j] = __builtin_amdgcn_fmed3f(x, ma[j], Ma[j]);
        }
        // pairwise tree sum (short dep chains)
        #pragma unroll
        for (int w = 8; w > 0; w >>= 1)
            #pragma unroll
            for (int j = 0; j < w; ++j)
                t[j] += t[j + w];
        float s = t[0];
        #pragma unroll
        for (int o = 32; o > 0; o >>= 1) s += __shfl_xor(s, o, 64);

        const int p = it & 1;
        if (lane == 0) wsum[p][wid] = s;
        __syncthreads();
        // write to wsum[p] at iter it is protected from iter it-2's reads of
        // wsum[p] by the barrier in iter it-1 -> single barrier suffices.
        const float gmid = (wsum[p][0] + wsum[p][1] + wsum[p][2] + wsum[p][3]) - xir;
        if (gmid > 0.0f) hi = mid; else lo = mid;
    }

    const float lam = 0.5f * (lo + hi);

    // ---- final x ----
    #pragma unroll
    for (int k = 0; k < 4; ++k) {
        const int idx = tid + k * 256;
        float4 r;
        float xs[4];
        #pragma unroll
        for (int c = 0; c < 4; ++c) {
            const int j = 4 * k + c;
            const float x = fmaf(lam, ia[j], za[j]);
            xs[c] = __builtin_amdgcn_fmed3f(x, ma[j], Ma[j]);
        }
        r.x = xs[0]; r.y = xs[1]; r.z = xs[2]; r.w = xs[3];
        orow[idx] = r;
    }
}

extern "C" void kernel_launch(void* const* d_in, const int* in_sizes, int n_in,
                              void* d_out, int out_size, void* d_ws, size_t ws_size,
                              hipStream_t stream) {
    const float* z     = (const float*)d_in[0];
    const float* gamma = (const float*)d_in[1];
    const float* m     = (const float*)d_in[2];
    const float* M     = (const float*)d_in[3];
    const float* xi    = (const float*)d_in[4];
    float* out = (float*)d_out;

    const int B = in_sizes[4];   // rows (xi has one entry per row)
    // Kernel is specialized to N == 4096 (16 elements / thread, 256 threads).
    qp_proj_n4096<<<dim3(B), dim3(256), 0, stream>>>(z, gamma, m, M, xi, out);
}

// Round 3
// 35.988 us; speedup vs baseline: 3.3442x; 1.2110x over previous
//
#include <hip/hip_runtime.h>

// Separable QP projection via bisection on lambda.
// One 256-thread block per row (B=4096, N=4096).
// Each thread owns 16 elements of the row in registers across all
// bisection iterations (z, 1/(2*gamma), m, M).
// Per iteration: 16x {fma, med3, add} per thread, DPP wave reduce (VALU
// pipe, no LDS-pipe shuffles), double-buffered 4-slot LDS combine with
// ONE barrier/iter, uniform lo/hi update.
//
// ITERS=12: initial interval width <= ~18, final width 18/2^12 = 4.4e-3
// -> lam err <= 2.2e-3 -> x err <= ~1.1e-3; plus ~4e-3 fp32 summation-
// noise floor (branch-flip vs reference) -> absmax ~5e-3 vs 2e-2 thr.

#define BISECT_ITERS 12

// ---- DPP wave64 reduction helpers (gfx9-family row ops) ----
// update_dpp(old, src, ctrl, row_mask, bank_mask, bound_ctrl=false):
// lanes with invalid fetch / masked rows return `old` (the identity).

template<int CTRL, int RM>
__device__ __forceinline__ float dpp_add(float v) {
    int t = __builtin_amdgcn_update_dpp(0, __float_as_int(v), CTRL, RM, 0xf, false);
    return v + __int_as_float(t);
}
template<int CTRL, int RM>
__device__ __forceinline__ float dpp_min(float v) {
    int t = __builtin_amdgcn_update_dpp(0x7f800000, __float_as_int(v), CTRL, RM, 0xf, false);
    return fminf(v, __int_as_float(t));
}
template<int CTRL, int RM>
__device__ __forceinline__ float dpp_max(float v) {
    int t = __builtin_amdgcn_update_dpp(0xff800000, __float_as_int(v), CTRL, RM, 0xf, false);
    return fmaxf(v, __int_as_float(t));
}

// After row_shr 1,2,4,8: lane 15/31/47/63 hold their 16-lane row sums.
// row_bcast:15 (rows 1,3) folds row0->row1, row2->row3 (lanes 31, 63).
// row_bcast:31 (rows 2,3) folds lower half -> upper (lane 63 = total).
__device__ __forceinline__ float wave_sum(float v) {
    v = dpp_add<0x111, 0xf>(v);   // row_shr:1
    v = dpp_add<0x112, 0xf>(v);   // row_shr:2
    v = dpp_add<0x114, 0xf>(v);   // row_shr:4
    v = dpp_add<0x118, 0xf>(v);   // row_shr:8
    v = dpp_add<0x142, 0xa>(v);   // row_bcast:15
    v = dpp_add<0x143, 0xc>(v);   // row_bcast:31
    return __int_as_float(__builtin_amdgcn_readlane(__float_as_int(v), 63));
}
__device__ __forceinline__ float wave_min(float v) {
    v = dpp_min<0x111, 0xf>(v);
    v = dpp_min<0x112, 0xf>(v);
    v = dpp_min<0x114, 0xf>(v);
    v = dpp_min<0x118, 0xf>(v);
    v = dpp_min<0x142, 0xa>(v);
    v = dpp_min<0x143, 0xc>(v);
    return __int_as_float(__builtin_amdgcn_readlane(__float_as_int(v), 63));
}
__device__ __forceinline__ float wave_max(float v) {
    v = dpp_max<0x111, 0xf>(v);
    v = dpp_max<0x112, 0xf>(v);
    v = dpp_max<0x114, 0xf>(v);
    v = dpp_max<0x118, 0xf>(v);
    v = dpp_max<0x142, 0xa>(v);
    v = dpp_max<0x143, 0xc>(v);
    return __int_as_float(__builtin_amdgcn_readlane(__float_as_int(v), 63));
}

__global__ __launch_bounds__(256) void qp_proj_n4096(
    const float* __restrict__ z,
    const float* __restrict__ gamma,
    const float* __restrict__ mlo,
    const float* __restrict__ mhi,
    const float* __restrict__ xi,
    float* __restrict__ out)
{
    constexpr int N = 4096;
    const int row  = blockIdx.x;
    const int tid  = threadIdx.x;     // 0..255
    const int lane = tid & 63;
    const int wid  = tid >> 6;        // 0..3

    const float4* zrow = reinterpret_cast<const float4*>(z + (size_t)row * N);
    const float4* g4   = reinterpret_cast<const float4*>(gamma);
    const float4* m4   = reinterpret_cast<const float4*>(mlo);
    const float4* M4   = reinterpret_cast<const float4*>(mhi);
    float4*       orow = reinterpret_cast<float4*>(out + (size_t)row * N);

    // Per-thread element state (static indices after full unroll -> registers).
    float za[16], ia[16], ma[16], Ma[16];

    float pmin =  INFINITY;   // partial min of 2g*(m - z)
    float pmax = -INFINITY;   // partial max of 2g*(M - z)

    #pragma unroll
    for (int k = 0; k < 4; ++k) {
        const int idx = tid + k * 256;           // float4 index, coalesced
        const float4 zz = zrow[idx];
        const float4 gg = g4[idx];
        const float4 mm = m4[idx];
        const float4 MM = M4[idx];

        const float zs[4] = {zz.x, zz.y, zz.z, zz.w};
        const float gs[4] = {gg.x, gg.y, gg.z, gg.w};
        const float ms[4] = {mm.x, mm.y, mm.z, mm.w};
        const float Ms[4] = {MM.x, MM.y, MM.z, MM.w};

        #pragma unroll
        for (int c = 0; c < 4; ++c) {
            const int j = 4 * k + c;
            const float tg = 2.0f * gs[c];
            za[j] = zs[c];
            ia[j] = 1.0f / tg;
            ma[j] = ms[c];
            Ma[j] = Ms[c];
            pmin = fminf(pmin, tg * (ms[c] - zs[c]));
            pmax = fmaxf(pmax, tg * (Ms[c] - zs[c]));
        }
    }

    // ---- block reduce initial bounds ----
    __shared__ float wmin[4], wmax[4];
    __shared__ float wsum[2][4];      // double-buffered: one barrier per iter

    pmin = wave_min(pmin);            // uniform per wave (SGPR)
    pmax = wave_max(pmax);
    if (lane == 0) { wmin[wid] = pmin; wmax[wid] = pmax; }
    __syncthreads();
    float lo = fminf(fminf(wmin[0], wmin[1]), fminf(wmin[2], wmin[3]));
    float hi = fmaxf(fmaxf(wmax[0], wmax[1]), fmaxf(wmax[2], wmax[3]));

    const float xir = xi[row];

    // ---- bisection ----
    for (int it = 0; it < BISECT_ITERS; ++it) {
        const float mid = 0.5f * (lo + hi);
        float t[16];
        #pragma unroll
        for (int j = 0; j < 16; ++j) {
            const float x = fmaf(mid, ia[j], za[j]);
            t[j] = __builtin_amdgcn_fmed3f(x, ma[j], Ma[j]);
        }
        // pairwise tree sum (short dep chains)
        #pragma unroll
        for (int w = 8; w > 0; w >>= 1)
            #pragma unroll
            for (int j = 0; j < w; ++j)
                t[j] += t[j + w];
        const float s = wave_sum(t[0]);

        const int p = it & 1;
        if (lane == 0) wsum[p][wid] = s;
        __syncthreads();
        // write to wsum[p] at iter it is protected from iter it-2's reads of
        // wsum[p] by the barrier in iter it-1 -> single barrier suffices.
        const float gmid = (wsum[p][0] + wsum[p][1] + wsum[p][2] + wsum[p][3]) - xir;
        if (gmid > 0.0f) hi = mid; else lo = mid;
    }

    const float lam = 0.5f * (lo + hi);

    // ---- final x ----
    #pragma unroll
    for (int k = 0; k < 4; ++k) {
        const int idx = tid + k * 256;
        float4 r;
        float xs[4];
        #pragma unroll
        for (int c = 0; c < 4; ++c) {
            const int j = 4 * k + c;
            const float x = fmaf(lam, ia[j], za[j]);
            xs[c] = __builtin_amdgcn_fmed3f(x, ma[j], Ma[j]);
        }
        r.x = xs[0]; r.y = xs[1]; r.z = xs[2]; r.w = xs[3];
        orow[idx] = r;
    }
}

extern "C" void kernel_launch(void* const* d_in, const int* in_sizes, int n_in,
                              void* d_out, int out_size, void* d_ws, size_t ws_size,
                              hipStream_t stream) {
    const float* z     = (const float*)d_in[0];
    const float* gamma = (const float*)d_in[1];
    const float* m     = (const float*)d_in[2];
    const float* M     = (const float*)d_in[3];
    const float* xi    = (const float*)d_in[4];
    float* out = (float*)d_out;

    const int B = in_sizes[4];   // rows (xi has one entry per row)
    // Kernel is specialized to N == 4096 (16 elements / thread, 256 threads).
    qp_proj_n4096<<<dim3(B), dim3(256), 0, stream>>>(z, gamma, m, M, xi, out);
}